// Round 29
// baseline (286.420 us; speedup 1.0000x reference)
//
#include <hip/hip_runtime.h>
#include <stdint.h>

// Problem constants (B=4, S=1024, H=2048, NH=16, MAXLEN=1024)
#define HDIM 2048
#define SEQLEN 1024
#define NHEADS 16
#define HEADD 128

typedef unsigned short u16;
typedef unsigned int u32;
typedef __attribute__((ext_vector_type(8))) short bf16x8;   // MFMA A/B frag
typedef __attribute__((ext_vector_type(8))) u16 u16x8;
typedef __attribute__((ext_vector_type(4))) u16 u16x4;
typedef __attribute__((ext_vector_type(4))) float f32x4;

__device__ __forceinline__ float bf2f(u16 u) {
    union { u32 i; float f; } v; v.i = ((u32)u) << 16; return v.f;
}
__device__ __forceinline__ u16 f2bf(float f) {
    union { float f; u32 i; } v; v.f = f;
    return (u16)((v.i + 0x7fffu + ((v.i >> 16) & 1u)) >> 16);  // RNE
}
__device__ __forceinline__ u16 f2bf_t(float f) {               // truncation (1 op)
    union { float f; u32 i; } v; v.f = f; return (u16)(v.i >> 16);
}
// Fast silu: x * rcp(1+exp(-x)).
__device__ __forceinline__ float silu_f(float x) {
    return x * __builtin_amdgcn_rcpf(1.f + __expf(-x));
}
// Async global->LDS, 16B per lane. LDS dest = wave-uniform base + lane*16.
__device__ __forceinline__ void glds16(const void* g, void* l) {
    __builtin_amdgcn_global_load_lds(
        (const __attribute__((address_space(1))) u32*)g,
        (__attribute__((address_space(3))) u32*)l, 16, 0, 0);
}

// ---------------------------------------------------------------------------
// Helpers for fused aux dispatches.
// cvt8: one 8-elem f32->bf16 chunk per thread, single-shot (bid in [0,4096)).
__device__ __forceinline__ void cvt8(const float* __restrict__ in,
                                     u16* __restrict__ out, int bid) {
    const int i = bid * 256 + threadIdx.x;     // < 1048576 = 4096*2048/8
    f32x4 a = *(const f32x4*)&in[(size_t)i * 8];
    f32x4 b = *(const f32x4*)&in[(size_t)i * 8 + 4];
    u16x8 o;
#pragma unroll
    for (int j = 0; j < 4; ++j) { o[j] = f2bf(a[j]); o[4 + j] = f2bf(b[j]); }
    *(u16x8*)&out[(size_t)i * 8] = o;
}

// transpose_tile: 64x64 tile tid (0..1023) of W[k][n] (f32) -> WT[n][k] bf16.
__device__ __forceinline__ void transpose_tile(const float* __restrict__ W,
                                               u16* __restrict__ WT, int tid) {
    __shared__ u16 T[64][76];   // 152B rows: 8B aligned, 4-way max on reads
    const int r0 = (tid >> 5) * 64;   // k
    const int c0 = (tid & 31) * 64;   // n
    const int t = threadIdx.x;
#pragma unroll
    for (int c = t; c < 1024; c += 256) {
        const int r = c >> 4, cc = (c & 15) << 2;
        f32x4 v = *(const f32x4*)&W[(size_t)(r0 + r) * HDIM + c0 + cc];
        u16x4 o;
#pragma unroll
        for (int j = 0; j < 4; ++j) o[j] = f2bf(v[j]);
        *(u16x4*)&T[r][cc] = o;
    }
    __syncthreads();
#pragma unroll
    for (int c = t; c < 512; c += 256) {
        const int n = c >> 3, kc = (c & 7) << 3;   // lanes 0-7: same n, kc 0..56
        u16x8 v;
#pragma unroll
        for (int j = 0; j < 8; ++j) v[j] = T[kc + j][n];
        *(u16x8*)&WT[(size_t)(c0 + n) * HDIM + r0 + kc] = v;
    }
}

// aux_qu: blocks [0,4096) cvt query; [4096,5120) trans Wq; [5120,6144) trans Wu.
__global__ __launch_bounds__(256) void aux_qu(
    const float* __restrict__ q, u16* __restrict__ qbf,
    const float* __restrict__ Wq, u16* __restrict__ WTq,
    const float* __restrict__ Wu, u16* __restrict__ WTu) {
    const int bid = blockIdx.x;
    if (bid < 4096)        cvt8(q, qbf, bid);
    else if (bid < 5120)   transpose_tile(Wq, WTq, bid - 4096);
    else                   transpose_tile(Wu, WTu, bid - 5120);
}

// aux_kv: [0,4096) cvt key; [4096,8192) cvt value; [8192,9216) trans Wk;
// [9216,10240) trans Wv.
__global__ __launch_bounds__(256) void aux_kv(
    const float* __restrict__ k, u16* __restrict__ kbf,
    const float* __restrict__ v, u16* __restrict__ vbf,
    const float* __restrict__ Wk, u16* __restrict__ WTk,
    const float* __restrict__ Wv, u16* __restrict__ WTv) {
    const int bid = blockIdx.x;
    if (bid < 4096)        cvt8(k, kbf, bid);
    else if (bid < 8192)   cvt8(v, vbf, bid - 4096);
    else if (bid < 9216)   transpose_tile(Wk, WTk, bid - 8192);
    else                   transpose_tile(Wv, WTv, bid - 9216);
}

// ---------------------------------------------------------------------------
// 128x128 GEMM core, clean double-buffer, 1 barrier/K-tile (round-24 body,
// verified).  mode 0: silu->bf16; mode 1: bias->f32; mode 2: silu->bf16
// transposed into VTg[(bh*128+d)*1024+s] via padded LDS.
// m0 = output row base; n0 = output col base within the 2048-wide target
// (also the WT row base).
__device__ __forceinline__ void gemm128_core(
    const u16* __restrict__ X, const u16* __restrict__ WT,
    const float* __restrict__ bias, void* __restrict__ outp,
    const int mode, const int m0, const int n0, u16* lds)
{
    const int t = threadIdx.x;
    const int lane = t & 63, wid = t >> 6;       // 4 waves
    const int l15 = lane & 15, l4 = lane >> 4;
    const int wr = wid >> 1, wn = wid & 1;

    const int ric = t >> 3;
    const int cse = (((t & 7) ^ (ric & 7)) << 3);
    const u16* gA = X  + (size_t)(m0 + ric) * HDIM + cse;
    const u16* gB = WT + (size_t)(n0 + ric) * HDIM + cse;

    u16* buf0 = lds;
    u16* buf1 = lds + 16384;
    const int wbase = wid * 512;

    int offA[4][2], offB[4][2];
#pragma unroll
    for (int i = 0; i < 4; ++i) {
        const int row = wr * 64 + i * 16 + l15;
#pragma unroll
        for (int kk = 0; kk < 2; ++kk)
            offA[i][kk] = ((row * 128 + kk * 64 + l4 * 16) ^ ((row & 7) << 4)) >> 1;
    }
#pragma unroll
    for (int j = 0; j < 4; ++j) {
        const int row = wn * 64 + j * 16 + l15;
#pragma unroll
        for (int kk = 0; kk < 2; ++kk)
            offB[j][kk] = 8192 + ((((row * 128 + kk * 64 + l4 * 16) ^ ((row & 7) << 4))) >> 1);
    }

#define STAGE_ALL(buf, kt) do {                                                 \
    glds16(gB + (size_t)0 * 32 * HDIM + (kt) * 64, (buf) + 8192 + 0 * 2048 + wbase); \
    glds16(gB + (size_t)1 * 32 * HDIM + (kt) * 64, (buf) + 8192 + 1 * 2048 + wbase); \
    glds16(gB + (size_t)2 * 32 * HDIM + (kt) * 64, (buf) + 8192 + 2 * 2048 + wbase); \
    glds16(gB + (size_t)3 * 32 * HDIM + (kt) * 64, (buf) + 8192 + 3 * 2048 + wbase); \
    glds16(gA + (size_t)0 * 32 * HDIM + (kt) * 64, (buf) + 0 * 2048 + wbase);   \
    glds16(gA + (size_t)1 * 32 * HDIM + (kt) * 64, (buf) + 1 * 2048 + wbase);   \
    glds16(gA + (size_t)2 * 32 * HDIM + (kt) * 64, (buf) + 2 * 2048 + wbase);   \
    glds16(gA + (size_t)3 * 32 * HDIM + (kt) * 64, (buf) + 3 * 2048 + wbase);   \
} while (0)

    STAGE_ALL(buf0, 0);
    asm volatile("s_waitcnt vmcnt(0)" ::: "memory");
    __builtin_amdgcn_s_barrier();

    f32x4 acc[4][4] = {};
    u16* pc = buf0;
    u16* pn = buf1;

#pragma unroll 1
    for (int tt = 0; tt < 32; ++tt) {
        if (tt + 1 < 32) STAGE_ALL(pn, tt + 1);
        bf16x8 bfr[4][2], afr[4][2];
#pragma unroll
        for (int j = 0; j < 4; ++j)
#pragma unroll
            for (int kk = 0; kk < 2; ++kk)
                bfr[j][kk] = *(const bf16x8*)(pc + offB[j][kk]);
#pragma unroll
        for (int i = 0; i < 4; ++i)
#pragma unroll
            for (int kk = 0; kk < 2; ++kk)
                afr[i][kk] = *(const bf16x8*)(pc + offA[i][kk]);
        __builtin_amdgcn_s_setprio(1);
#pragma unroll
        for (int i = 0; i < 4; ++i)
#pragma unroll
            for (int j = 0; j < 4; ++j)
#pragma unroll
                for (int kk = 0; kk < 2; ++kk)
                    acc[i][j] = __builtin_amdgcn_mfma_f32_16x16x32_bf16(
                        afr[i][kk], bfr[j][kk], acc[i][j], 0, 0, 0);
        __builtin_amdgcn_s_setprio(0);
        if (tt + 1 < 32) { asm volatile("s_waitcnt vmcnt(0)" ::: "memory"); }
        __builtin_amdgcn_s_barrier();
        u16* tmp = pc; pc = pn; pn = tmp;
    }
#undef STAGE_ALL

    float bvv[4];
#pragma unroll
    for (int j = 0; j < 4; ++j) bvv[j] = bias[n0 + wn * 64 + j * 16 + l15];

    if (mode == 2) {
        u16* Tv = lds;
        __syncthreads();
#pragma unroll
        for (int i = 0; i < 4; ++i)
#pragma unroll
            for (int r = 0; r < 4; ++r) {
                const int s = wr * 64 + i * 16 + (l4 << 2) + r;
#pragma unroll
                for (int j = 0; j < 4; ++j) {
                    const int d = wn * 64 + j * 16 + l15;
                    Tv[d * 136 + s] = f2bf(silu_f(acc[i][j][r] + bvv[j]));
                }
            }
        __syncthreads();
        const int tn = n0 >> 7;
        const int bh = (m0 >> 10) * 16 + tn;     // b*16 + h
        const int s0 = m0 & 1023;
        u16* vt = (u16*)outp;
#pragma unroll
        for (int r8 = 0; r8 < 8; ++r8) {
            const int d = (t >> 4) + r8 * 16;
            const int s = (t & 15) * 8;
            u16x8 v = *(const u16x8*)&Tv[d * 136 + s];
            *(u16x8*)&vt[((size_t)bh * HEADD + d) * SEQLEN + s0 + s] = v;
        }
        return;
    }

#pragma unroll
    for (int i = 0; i < 4; ++i) {
        const int mbase = m0 + wr * 64 + i * 16 + (l4 << 2);
#pragma unroll
        for (int r = 0; r < 4; ++r) {
            const size_t rowoff = (size_t)(mbase + r) * HDIM + n0 + wn * 64 + l15;
#pragma unroll
            for (int j = 0; j < 4; ++j) {
                const float v = acc[i][j][r] + bvv[j];
                if (mode == 0)
                    ((u16*)outp)[rowoff + j * 16] = f2bf(silu_f(v));
                else
                    ((float*)outp)[rowoff + j * 16] = v;
            }
        }
    }
}

// Standard 512-block wrapper (K / V / final projections).
__global__ __launch_bounds__(256) void gemm128(
    const u16* __restrict__ X, const u16* __restrict__ WT,
    const float* __restrict__ bias, void* __restrict__ outp, const int mode)
{
    extern __shared__ u16 lds[];
    const int bid = blockIdx.x;                  // 512 blocks
    const int u = (bid & 7) * 64 + (bid >> 3);   // XCD-bijective
    const int tm = u & 31, tn = u >> 5;
    gemm128_core(X, WT, bias, outp, mode, tm * 128, tn * 128, lds);
}

// QU-fused wrapper: 1024 blocks over the concatenated Q|U output (N=4096).
// Single A stream (query_bf); per-XCD decode gives each XCD one weight
// matrix (tn block of 4) -> no cross-stream L2 thrash (round-23 lesson).
__global__ __launch_bounds__(256) void gemm128_qu(
    const u16* __restrict__ X,
    const u16* __restrict__ WTq, const u16* __restrict__ WTu,
    const float* __restrict__ bq, const float* __restrict__ bu,
    u16* __restrict__ Qo, u16* __restrict__ Uo)
{
    extern __shared__ u16 lds[];
    const int bid = blockIdx.x;                   // 1024 blocks
    const int u = (bid & 7) * 128 + (bid >> 3);   // XCD-bijective
    const int tm = u & 31, tn = u >> 5;           // 32 M x 32 N tiles
    const int n0 = tn * 128;                      // 0..4095
    const u16* WT = (n0 < 2048) ? WTq : WTu;
    const float* bias = (n0 < 2048) ? bq : bu;
    u16* outp = (n0 < 2048) ? Qo : Uo;
    gemm128_core(X, WT, bias, outp, 0, tm * 128, n0 & 2047, lds);
}

// ---------------------------------------------------------------------------
// Fused SiLU-attention + gating, 8-wave split + diagonal-branch (round-24),
// with the Wf2 transpose folded in: blocks [512,1536) each transpose one
// 64x64 tile of Wf2 into WTf (using the dynamic LDS buffer, 512 threads) —
// they run in the shadow of attention's causal tail imbalance.
__global__ __launch_bounds__(512) void attn_fused(
    const u16* __restrict__ Qb, const u16* __restrict__ Kb,
    const u16* __restrict__ VTg, const u16* __restrict__ Ub,
    const float* __restrict__ rel, u16* __restrict__ G,
    const float* __restrict__ Wf2, u16* __restrict__ WTf)
{
    extern __shared__ u16 alds[];

    if (blockIdx.x >= 512) {
        // ---- Wf2 transpose tile (512-thread variant, dynamic LDS) ----
        u16* T = alds;                         // [64][76]
        const int tid = blockIdx.x - 512;      // 0..1023
        const int r0 = (tid >> 5) * 64;        // k
        const int c0 = (tid & 31) * 64;        // n
        const int t = threadIdx.x;
#pragma unroll
        for (int c = t; c < 1024; c += 512) {
            const int r = c >> 4, cc = (c & 15) << 2;
            f32x4 v = *(const f32x4*)&Wf2[(size_t)(r0 + r) * HDIM + c0 + cc];
            u16x4 o;
#pragma unroll
            for (int j = 0; j < 4; ++j) o[j] = f2bf(v[j]);
            *(u16x4*)&T[r * 76 + cc] = o;
        }
        __syncthreads();
        {
            const int c = t & 511;             // 0..511, all used
            const int n = c >> 3, kc = (c & 7) << 3;
            u16x8 v;
#pragma unroll
            for (int j = 0; j < 8; ++j) v[j] = T[(kc + j) * 76 + n];
            *(u16x8*)&WTf[(size_t)(c0 + n) * HDIM + r0 + kc] = v;
        }
        return;
    }

    u16* Ps = alds + 24576;
    float* relh = (float*)(alds + 33792);

    const int idx = blockIdx.x;
    const int bh8 = idx & 7;
    const int j = (idx >> 3) & 7;
    const int bhhi = idx >> 6;            // 0..7
    const int bh = bhhi * 8 + bh8;
    const int b = bh >> 4, h = bh & 15;
    const int qS0 = j * 64;               // short subtile
    const int qL0 = (15 - j) * 64;        // long subtile
    const int nkt = 16 - j;
    const int t = threadIdx.x, lane = t & 63, w = t >> 6;    // 8 waves
    const int wq = w & 3;
    const bool isL = (w < 4);
    const int l15 = lane & 15, l4 = lane >> 4, l3 = lane >> 3;
    const size_t rowbase = (size_t)b * SEQLEN;
    const int col0 = h * HEADD;
    const float scale = 0.088388347648318447f;   // 1/sqrt(128)

    for (int i = t; i < 1024; i += 512) relh[i] = rel[(size_t)(1023 + i) * NHEADS + h];

    const u16* gK0 = Kb + (rowbase + w * 8 + l4) * HDIM + col0 + ((lane & 15) ^ l4) * 8;
    const u16* gK1 = Kb + (rowbase + w * 8 + 4 + l4) * HDIM + col0 + ((lane & 15) ^ (l4 + 4)) * 8;
    const u16* gV0 = VTg + ((size_t)bh * HEADD + w * 16 + l3) * SEQLEN + ((lane & 7) ^ l3) * 8;
    const u16* gV1 = VTg + ((size_t)bh * HEADD + w * 16 + 8 + l3) * SEQLEN + ((lane & 7) ^ l3) * 8;

    const int q0 = (isL ? qL0 : qS0) + wq * 16;
    bf16x8 aq[4];
#pragma unroll
    for (int dc = 0; dc < 4; ++dc)
        aq[dc] = *(const bf16x8*)&Qb[(rowbase + q0 + l15) * HDIM + col0 + dc * 32 + (l4 << 3)];

    f32x4 oacc[8] = {};
    const int prB = (isL ? 0 : 64) + wq * 16;     // Ps row base for this wave

#define STAGE_K(kt) do {                                                        \
    const size_t ko_ = (size_t)(kt) * 64 * HDIM;                                \
    glds16(gK0 + ko_, alds + w * 1024);                                         \
    glds16(gK1 + ko_, alds + w * 1024 + 512);                                   \
} while (0)
#define STAGE_V(kt, bsel) do {                                                  \
    u16* vb_ = alds + 8192 + ((bsel) ? 8192 : 0);                               \
    const size_t ko_ = (size_t)(kt) * 64;                                       \
    glds16(gV0 + ko_, vb_ + w * 1024);                                          \
    glds16(gV1 + ko_, vb_ + w * 1024 + 512);                                    \
} while (0)

    STAGE_K(0); STAGE_V(0, 0);
    asm volatile("s_waitcnt vmcnt(0)" ::: "memory");
    __builtin_amdgcn_s_barrier();

    int cur = 0;
#pragma unroll 1
    for (int kt = 0; kt < nkt; ++kt) {
        const int k0 = kt * 64;
        const bool act = isL || (kt <= j);        // wave-uniform
        const bool diag = isL ? (kt == nkt - 1) : (kt == j);
        if (kt + 1 < nkt) STAGE_V(kt + 1, cur ^ 1);
        const u16* kb = alds;
        const u16* vb = alds + 8192 + (cur ? 8192 : 0);

        // QK^T + rel (+ mask only on diag tile) + silu -> Ps
        if (act) {
#pragma unroll
            for (int kf = 0; kf < 4; ++kf) {
                const int krow = kf * 16 + l15;
                f32x4 s = {};
                __builtin_amdgcn_s_setprio(1);
#pragma unroll
                for (int dc = 0; dc < 4; ++dc) {
                    bf16x8 bk = *(const bf16x8*)&kb[krow * 128 + (((dc * 4 + l4) ^ (krow & 7)) << 3)];
                    s = __builtin_amdgcn_mfma_f32_16x16x32_bf16(aq[dc], bk, s, 0, 0, 0);
                }
                __builtin_amdgcn_s_setprio(0);
                const int kabs = k0 + krow;
                const int pr = prB + (l4 << 2);
                if (diag) {
#pragma unroll
                    for (int r = 0; r < 4; ++r) {
                        const int qabs = q0 + (l4 << 2) + r;
                        float v = 0.f;
                        if (kabs <= qabs) v = silu_f(fmaf(s[r], scale, relh[qabs - kabs]));
                        Ps[(pr + r) * 72 + kf * 16 + l15] = f2bf_t(v);
                    }
                } else {
#pragma unroll
                    for (int r = 0; r < 4; ++r) {
                        const int qabs = q0 + (l4 << 2) + r;
                        const float v = silu_f(fmaf(s[r], scale, relh[qabs - kabs]));
                        Ps[(pr + r) * 72 + kf * 16 + l15] = f2bf_t(v);
                    }
                }
            }
        }
        __builtin_amdgcn_s_barrier();                 // Kbuf free (QK^T reads done)
        if (kt + 1 < nkt) STAGE_K(kt + 1);

        // PV (active waves only)
        if (act) {
            bf16x8 ap[2];
#pragma unroll
            for (int kc = 0; kc < 2; ++kc)
                ap[kc] = *(const bf16x8*)&Ps[(prB + l15) * 72 + kc * 32 + (l4 << 3)];
            __builtin_amdgcn_s_setprio(1);
#pragma unroll
            for (int df = 0; df < 8; ++df) {
                const int vrow = df * 16 + l15;
#pragma unroll
                for (int kc = 0; kc < 2; ++kc) {
                    bf16x8 bv = *(const bf16x8*)&vb[vrow * 64 + (((kc * 4 + l4) ^ (vrow & 7)) << 3)];
                    oacc[df] = __builtin_amdgcn_mfma_f32_16x16x32_bf16(ap[kc], bv, oacc[df], 0, 0, 0);
                }
            }
            __builtin_amdgcn_s_setprio(0);
        }
        asm volatile("s_waitcnt vmcnt(0)" ::: "memory");  // next K,V landed
        __builtin_amdgcn_s_barrier();
        cur ^= 1;
    }
#undef STAGE_K
#undef STAGE_V

    // G = O * U (each wave its own 16 rows), row-sweep for coalescing
#pragma unroll
    for (int r = 0; r < 4; ++r) {
        const int qr = q0 + (l4 << 2) + r;
        const size_t row = (rowbase + qr) * HDIM + col0 + l15;
#pragma unroll
        for (int df = 0; df < 8; ++df)
            G[row + df * 16] = f2bf(oacc[df][r] * bf2f(Ub[row + df * 16]));
    }
}

// ---------------------------------------------------------------------------
extern "C" void kernel_launch(void* const* d_in, const int* in_sizes, int n_in,
                              void* d_out, int out_size, void* d_ws, size_t ws_size,
                              hipStream_t stream) {
    const float* query = (const float*)d_in[0];
    const float* key_  = (const float*)d_in[1];
    const float* value = (const float*)d_in[2];
    // d_in[3] attn_mask: causal by construction, handled analytically.
    const float* Wq  = (const float*)d_in[4];  const float* bq  = (const float*)d_in[5];
    const float* Wk  = (const float*)d_in[6];  const float* bk  = (const float*)d_in[7];
    const float* Wv  = (const float*)d_in[8];  const float* bv  = (const float*)d_in[9];
    const float* Wu  = (const float*)d_in[10]; const float* bu  = (const float*)d_in[11];
    const float* Wf2 = (const float*)d_in[12]; const float* bf2 = (const float*)d_in[13];
    const float* rel = (const float*)d_in[14];

    // Workspace (88 MiB): WTa 8 | Xbf 16 | Q(=G) 16 | K 16 | VTg 16 | U 16.
    // d_out (32 MiB, fully rewritten by the final GEMM) used as scratch for
    // key_bf (16 MiB) + Wv^T (8 MiB).
    char* ws = (char*)d_ws;
    const size_t WBYTES = (size_t)HDIM * HDIM * 2;   // 8 MiB
    const size_t ABYTES = (size_t)4096 * HDIM * 2;   // 16 MiB
    u16* WTa  = (u16*)ws;
    u16* Xbf  = (u16*)(ws + WBYTES);
    u16* Qbuf = (u16*)(ws + WBYTES + 1 * ABYTES);
    u16* Kbuf = (u16*)(ws + WBYTES + 2 * ABYTES);
    u16* VTg  = (u16*)(ws + WBYTES + 3 * ABYTES);    // V written transposed here
    u16* Ubuf = (u16*)(ws + WBYTES + 4 * ABYTES);
    u16* WTb  = VTg;           // borrowed for Wu^T: freed before V GEMM writes VTg
    u16* Gbuf = Qbuf;          // attn reads its own Q rows, then writes them as G
    u16* KXbf = (u16*)d_out;                 // scratch in d_out
    u16* WTv  = (u16*)((char*)d_out + ABYTES);

    dim3 tpb(256);
    const size_t GLDS  = 65536;  // 64 KiB for gemm128 / gemm128_qu
    const size_t ALDS  = 71680;  // 70 KiB for attn_fused

    aux_qu<<<6144, tpb, 0, stream>>>(query, Xbf, Wq, WTa, Wu, WTb);
    gemm128_qu<<<1024, tpb, GLDS, stream>>>(Xbf, WTa, WTb, bq, bu, Qbuf, Ubuf);
    aux_kv<<<10240, tpb, 0, stream>>>(key_, KXbf, value, Xbf, Wk, WTa, Wv, WTv);
    gemm128<<<512, tpb, GLDS, stream>>>(KXbf, WTa, bk, Kbuf, 0);
    gemm128<<<512, tpb, GLDS, stream>>>(Xbf, WTv, bv, VTg, 2);
    // attn + folded Wf2 transpose (WTa is dead after the K GEMM)
    attn_fused<<<1536, 512, ALDS, stream>>>(Qbuf, Kbuf, VTg, Ubuf, rel, Gbuf,
                                            Wf2, WTa);
    gemm128<<<512, tpb, GLDS, stream>>>(Gbuf, WTa, bf2, d_out, 1);
}

// Round 30
// 280.182 us; speedup vs baseline: 1.0223x; 1.0223x over previous
//
#include <hip/hip_runtime.h>
#include <stdint.h>

// Problem constants (B=4, S=1024, H=2048, NH=16, MAXLEN=1024)
#define HDIM 2048
#define SEQLEN 1024
#define NHEADS 16
#define HEADD 128

typedef unsigned short u16;
typedef unsigned int u32;
typedef __attribute__((ext_vector_type(8))) short bf16x8;   // MFMA A/B frag
typedef __attribute__((ext_vector_type(8))) u16 u16x8;
typedef __attribute__((ext_vector_type(4))) u16 u16x4;
typedef __attribute__((ext_vector_type(4))) float f32x4;

__device__ __forceinline__ float bf2f(u16 u) {
    union { u32 i; float f; } v; v.i = ((u32)u) << 16; return v.f;
}
__device__ __forceinline__ u16 f2bf(float f) {
    union { float f; u32 i; } v; v.f = f;
    return (u16)((v.i + 0x7fffu + ((v.i >> 16) & 1u)) >> 16);  // RNE
}
__device__ __forceinline__ u16 f2bf_t(float f) {               // truncation (1 op)
    union { float f; u32 i; } v; v.f = f; return (u16)(v.i >> 16);
}
// Fast silu: x * rcp(1+exp(-x)).
__device__ __forceinline__ float silu_f(float x) {
    return x * __builtin_amdgcn_rcpf(1.f + __expf(-x));
}
// Async global->LDS, 16B per lane. LDS dest = wave-uniform base + lane*16.
__device__ __forceinline__ void glds16(const void* g, void* l) {
    __builtin_amdgcn_global_load_lds(
        (const __attribute__((address_space(1))) u32*)g,
        (__attribute__((address_space(3))) u32*)l, 16, 0, 0);
}

// ---------------------------------------------------------------------------
// Helpers for fused aux dispatches.
// cvt8: one 8-elem f32->bf16 chunk per thread, single-shot (bid in [0,4096)).
__device__ __forceinline__ void cvt8(const float* __restrict__ in,
                                     u16* __restrict__ out, int bid) {
    const int i = bid * 256 + threadIdx.x;     // < 1048576 = 4096*2048/8
    f32x4 a = *(const f32x4*)&in[(size_t)i * 8];
    f32x4 b = *(const f32x4*)&in[(size_t)i * 8 + 4];
    u16x8 o;
#pragma unroll
    for (int j = 0; j < 4; ++j) { o[j] = f2bf(a[j]); o[4 + j] = f2bf(b[j]); }
    *(u16x8*)&out[(size_t)i * 8] = o;
}

// transpose_tile: 64x64 tile tid (0..1023) of W[k][n] (f32) -> WT[n][k] bf16.
__device__ __forceinline__ void transpose_tile(const float* __restrict__ W,
                                               u16* __restrict__ WT, int tid) {
    __shared__ u16 T[64][76];   // 152B rows: 8B aligned, 4-way max on reads
    const int r0 = (tid >> 5) * 64;   // k
    const int c0 = (tid & 31) * 64;   // n
    const int t = threadIdx.x;
#pragma unroll
    for (int c = t; c < 1024; c += 256) {
        const int r = c >> 4, cc = (c & 15) << 2;
        f32x4 v = *(const f32x4*)&W[(size_t)(r0 + r) * HDIM + c0 + cc];
        u16x4 o;
#pragma unroll
        for (int j = 0; j < 4; ++j) o[j] = f2bf(v[j]);
        *(u16x4*)&T[r][cc] = o;
    }
    __syncthreads();
#pragma unroll
    for (int c = t; c < 512; c += 256) {
        const int n = c >> 3, kc = (c & 7) << 3;   // lanes 0-7: same n, kc 0..56
        u16x8 v;
#pragma unroll
        for (int j = 0; j < 8; ++j) v[j] = T[kc + j][n];
        *(u16x8*)&WT[(size_t)(c0 + n) * HDIM + r0 + kc] = v;
    }
}

// aux_qu: blocks [0,4096) cvt query; [4096,5120) trans Wq; [5120,6144) trans Wu.
__global__ __launch_bounds__(256) void aux_qu(
    const float* __restrict__ q, u16* __restrict__ qbf,
    const float* __restrict__ Wq, u16* __restrict__ WTq,
    const float* __restrict__ Wu, u16* __restrict__ WTu) {
    const int bid = blockIdx.x;
    if (bid < 4096)        cvt8(q, qbf, bid);
    else if (bid < 5120)   transpose_tile(Wq, WTq, bid - 4096);
    else                   transpose_tile(Wu, WTu, bid - 5120);
}

// aux_kv: [0,4096) cvt key; [4096,8192) cvt value; [8192,9216) trans Wk;
// [9216,10240) trans Wv.
__global__ __launch_bounds__(256) void aux_kv(
    const float* __restrict__ k, u16* __restrict__ kbf,
    const float* __restrict__ v, u16* __restrict__ vbf,
    const float* __restrict__ Wk, u16* __restrict__ WTk,
    const float* __restrict__ Wv, u16* __restrict__ WTv) {
    const int bid = blockIdx.x;
    if (bid < 4096)        cvt8(k, kbf, bid);
    else if (bid < 8192)   cvt8(v, vbf, bid - 4096);
    else if (bid < 9216)   transpose_tile(Wk, WTk, bid - 8192);
    else                   transpose_tile(Wv, WTv, bid - 9216);
}

// ---------------------------------------------------------------------------
// 256x256 GEMM, QU-fused, 1-barrier-per-K-tile (round-24 best): all 8 loads
// of tile t+1 issued during Φ1 of tile t; tile-entry vmcnt(0)+barrier
// guarantees Φ2's A reads are resident.  Two 32-MFMA setprio clusters.
__global__ __launch_bounds__(512, 2) void gemm256_8p(
    const u16* __restrict__ X,
    const u16* __restrict__ WTq, const u16* __restrict__ WTu,
    const float* __restrict__ bq, const float* __restrict__ bu,
    u16* __restrict__ Qo, u16* __restrict__ Uo)
{
    extern __shared__ u16 lds[];   // 2 bufs x 32768 u16 (A @0, B @16384)
    const int t = threadIdx.x;
    const int lane = t & 63, wid = t >> 6;        // 8 waves
    const int l15 = lane & 15, l4 = lane >> 4;
    const int wr = wid >> 2, wn = wid & 3;        // 2M x 4N

    const int bid = blockIdx.x;                   // 256 blocks
    const int u = (bid & 7) * 32 + (bid >> 3);    // XCD-bijective
    const int tm = u & 15, tn = u >> 4;
    const int m0 = tm * 256;
    const int n0 = tn * 256;                      // 0..4095
    const u16* WT = (n0 < 2048) ? WTq : WTu;
    const float* bias = (n0 < 2048) ? bq : bu;
    u16* outp = (n0 < 2048) ? Qo : Uo;
    const int nc0 = n0 & 2047;

    const int r64 = t >> 3;                       // 0..63
    const int cse = (((t & 7) ^ (r64 & 7)) << 3);
    const u16* gA = X + (size_t)(m0 + r64) * HDIM + cse;
    const int rB0 = (r64 >> 5) * 64 + (r64 & 31);
    const u16* gB = WT + (size_t)(nc0 + rB0) * HDIM + cse;

    const int wbase = wid * 512;
    const int dstBw = (wid >> 2) * 4096 + (wid & 3) * 512;

    int offA[8][2], offB[4][2];
#pragma unroll
    for (int mf = 0; mf < 8; ++mf) {
        const int row = wr * 128 + mf * 16 + l15;
#pragma unroll
        for (int kk = 0; kk < 2; ++kk) {
            const int c = kk * 4 + l4;
            offA[mf][kk] = row * 64 + (((c) ^ (row & 7)) << 3);
        }
    }
#pragma unroll
    for (int nf = 0; nf < 4; ++nf) {
        const int row = wn * 64 + nf * 16 + l15;
#pragma unroll
        for (int kk = 0; kk < 2; ++kk) {
            const int c = kk * 4 + l4;
            offB[nf][kk] = 16384 + row * 64 + (((c) ^ (row & 7)) << 3);
        }
    }

#define SA(buf, rb, kt) glds16(gA + (size_t)(rb) * HDIM + (kt) * 64, \
                               lds + (buf) * 32768 + (rb) * 64 + wbase)
#define SB(buf, c, half, kt) glds16(gB + (size_t)((c) * 128 + (half) * 32) * HDIM + (kt) * 64, \
                               lds + (buf) * 32768 + 16384 + dstBw + (c) * 8192 + (half) * 2048)
#define SALL(buf, kt) do {                                                     \
    SA(buf, 0, kt); SA(buf, 64, kt); SA(buf, 128, kt); SA(buf, 192, kt);       \
    SB(buf, 0, 0, kt); SB(buf, 1, 0, kt); SB(buf, 0, 1, kt); SB(buf, 1, 1, kt);\
} while (0)

    SALL(0, 0);
    asm volatile("s_waitcnt vmcnt(0)" ::: "memory");
    __builtin_amdgcn_s_barrier();

    f32x4 acc[8][4] = {};
    int cur = 0;

#pragma unroll 1
    for (int kt = 0; kt < 32; ++kt) {
        const u16* pc = lds + cur * 32768;
        const int nb = cur ^ 1;
        const bool pf = (kt + 1 < 32);
        bf16x8 a[4][2], b[4][2];

        if (pf) SALL(nb, kt + 1);
#pragma unroll
        for (int mf = 0; mf < 4; ++mf)
#pragma unroll
            for (int kk = 0; kk < 2; ++kk)
                a[mf][kk] = *(const bf16x8*)(pc + offA[mf][kk]);
#pragma unroll
        for (int nf = 0; nf < 4; ++nf)
#pragma unroll
            for (int kk = 0; kk < 2; ++kk)
                b[nf][kk] = *(const bf16x8*)(pc + offB[nf][kk]);
        __builtin_amdgcn_s_setprio(1);
#pragma unroll
        for (int mf = 0; mf < 4; ++mf)
#pragma unroll
            for (int nf = 0; nf < 4; ++nf)
#pragma unroll
                for (int kk = 0; kk < 2; ++kk)
                    acc[mf][nf] = __builtin_amdgcn_mfma_f32_16x16x32_bf16(
                        a[mf][kk], b[nf][kk], acc[mf][nf], 0, 0, 0);
        __builtin_amdgcn_s_setprio(0);

#pragma unroll
        for (int mf = 0; mf < 4; ++mf)
#pragma unroll
            for (int kk = 0; kk < 2; ++kk)
                a[mf][kk] = *(const bf16x8*)(pc + offA[4 + mf][kk]);
        __builtin_amdgcn_s_setprio(1);
#pragma unroll
        for (int mf = 0; mf < 4; ++mf)
#pragma unroll
            for (int nf = 0; nf < 4; ++nf)
#pragma unroll
                for (int kk = 0; kk < 2; ++kk)
                    acc[4 + mf][nf] = __builtin_amdgcn_mfma_f32_16x16x32_bf16(
                        a[mf][kk], b[nf][kk], acc[4 + mf][nf], 0, 0, 0);
        __builtin_amdgcn_s_setprio(0);
        if (pf) { asm volatile("s_waitcnt vmcnt(0)" ::: "memory"); }
        __builtin_amdgcn_s_barrier();
        cur ^= 1;
    }
#undef SALL
#undef SA
#undef SB

    float bvv[4];
#pragma unroll
    for (int nf = 0; nf < 4; ++nf) bvv[nf] = bias[nc0 + wn * 64 + nf * 16 + l15];
#pragma unroll
    for (int mf = 0; mf < 8; ++mf) {
        const int mbase = m0 + wr * 128 + mf * 16 + (l4 << 2);
#pragma unroll
        for (int r = 0; r < 4; ++r) {
            u16* rowp = outp + (size_t)(mbase + r) * HDIM + nc0 + wn * 64 + l15;
#pragma unroll
            for (int nf = 0; nf < 4; ++nf)
                rowp[nf * 16] = f2bf(silu_f(acc[mf][nf][r] + bvv[nf]));
        }
    }
}

// ---------------------------------------------------------------------------
// 128x128 GEMM, clean double-buffer, 1 barrier/K-tile (round-24, unchanged).
// mode 0: silu->bf16; mode 1: bias->f32; mode 2: silu->bf16 transposed
// into VTg[(bh*128+d)*1024+s] via padded LDS.
__global__ __launch_bounds__(256) void gemm128(
    const u16* __restrict__ X, const u16* __restrict__ WT,
    const float* __restrict__ bias, void* __restrict__ outp, const int mode)
{
    extern __shared__ u16 lds[];
    const int t = threadIdx.x;
    const int lane = t & 63, wid = t >> 6;       // 4 waves
    const int l15 = lane & 15, l4 = lane >> 4;
    const int wr = wid >> 1, wn = wid & 1;

    const int bid = blockIdx.x;                  // 512 blocks
    const int u = (bid & 7) * 64 + (bid >> 3);   // XCD-bijective
    const int tm = u & 31, tn = u >> 5;
    const int m0 = tm * 128, n0 = tn * 128;

    const int ric = t >> 3;
    const int cse = (((t & 7) ^ (ric & 7)) << 3);
    const u16* gA = X  + (size_t)(m0 + ric) * HDIM + cse;
    const u16* gB = WT + (size_t)(n0 + ric) * HDIM + cse;

    u16* buf0 = lds;
    u16* buf1 = lds + 16384;
    const int wbase = wid * 512;

    int offA[4][2], offB[4][2];
#pragma unroll
    for (int i = 0; i < 4; ++i) {
        const int row = wr * 64 + i * 16 + l15;
#pragma unroll
        for (int kk = 0; kk < 2; ++kk)
            offA[i][kk] = ((row * 128 + kk * 64 + l4 * 16) ^ ((row & 7) << 4)) >> 1;
    }
#pragma unroll
    for (int j = 0; j < 4; ++j) {
        const int row = wn * 64 + j * 16 + l15;
#pragma unroll
        for (int kk = 0; kk < 2; ++kk)
            offB[j][kk] = 8192 + ((((row * 128 + kk * 64 + l4 * 16) ^ ((row & 7) << 4))) >> 1);
    }

#define STAGE_ALL(buf, kt) do {                                                 \
    glds16(gB + (size_t)0 * 32 * HDIM + (kt) * 64, (buf) + 8192 + 0 * 2048 + wbase); \
    glds16(gB + (size_t)1 * 32 * HDIM + (kt) * 64, (buf) + 8192 + 1 * 2048 + wbase); \
    glds16(gB + (size_t)2 * 32 * HDIM + (kt) * 64, (buf) + 8192 + 2 * 2048 + wbase); \
    glds16(gB + (size_t)3 * 32 * HDIM + (kt) * 64, (buf) + 8192 + 3 * 2048 + wbase); \
    glds16(gA + (size_t)0 * 32 * HDIM + (kt) * 64, (buf) + 0 * 2048 + wbase);   \
    glds16(gA + (size_t)1 * 32 * HDIM + (kt) * 64, (buf) + 1 * 2048 + wbase);   \
    glds16(gA + (size_t)2 * 32 * HDIM + (kt) * 64, (buf) + 2 * 2048 + wbase);   \
    glds16(gA + (size_t)3 * 32 * HDIM + (kt) * 64, (buf) + 3 * 2048 + wbase);   \
} while (0)

    STAGE_ALL(buf0, 0);
    asm volatile("s_waitcnt vmcnt(0)" ::: "memory");
    __builtin_amdgcn_s_barrier();

    f32x4 acc[4][4] = {};
    u16* pc = buf0;
    u16* pn = buf1;

#pragma unroll 1
    for (int tt = 0; tt < 32; ++tt) {
        if (tt + 1 < 32) STAGE_ALL(pn, tt + 1);
        bf16x8 bfr[4][2], afr[4][2];
#pragma unroll
        for (int j = 0; j < 4; ++j)
#pragma unroll
            for (int kk = 0; kk < 2; ++kk)
                bfr[j][kk] = *(const bf16x8*)(pc + offB[j][kk]);
#pragma unroll
        for (int i = 0; i < 4; ++i)
#pragma unroll
            for (int kk = 0; kk < 2; ++kk)
                afr[i][kk] = *(const bf16x8*)(pc + offA[i][kk]);
        __builtin_amdgcn_s_setprio(1);
#pragma unroll
        for (int i = 0; i < 4; ++i)
#pragma unroll
            for (int j = 0; j < 4; ++j)
#pragma unroll
                for (int kk = 0; kk < 2; ++kk)
                    acc[i][j] = __builtin_amdgcn_mfma_f32_16x16x32_bf16(
                        afr[i][kk], bfr[j][kk], acc[i][j], 0, 0, 0);
        __builtin_amdgcn_s_setprio(0);
        if (tt + 1 < 32) { asm volatile("s_waitcnt vmcnt(0)" ::: "memory"); }
        __builtin_amdgcn_s_barrier();
        u16* tmp = pc; pc = pn; pn = tmp;
    }
#undef STAGE_ALL

    float bvv[4];
#pragma unroll
    for (int j = 0; j < 4; ++j) bvv[j] = bias[n0 + wn * 64 + j * 16 + l15];

    if (mode == 2) {
        u16* Tv = lds;
        __syncthreads();
#pragma unroll
        for (int i = 0; i < 4; ++i)
#pragma unroll
            for (int r = 0; r < 4; ++r) {
                const int s = wr * 64 + i * 16 + (l4 << 2) + r;
#pragma unroll
                for (int j = 0; j < 4; ++j) {
                    const int d = wn * 64 + j * 16 + l15;
                    Tv[d * 136 + s] = f2bf(silu_f(acc[i][j][r] + bvv[j]));
                }
            }
        __syncthreads();
        const int bh = (m0 >> 10) * 16 + tn;     // b*16 + h
        const int s0 = m0 & 1023;
        u16* vt = (u16*)outp;
#pragma unroll
        for (int r8 = 0; r8 < 8; ++r8) {
            const int d = (t >> 4) + r8 * 16;
            const int s = (t & 15) * 8;
            u16x8 v = *(const u16x8*)&Tv[d * 136 + s];
            *(u16x8*)&vt[((size_t)bh * HEADD + d) * SEQLEN + s0 + s] = v;
        }
        return;
    }

#pragma unroll
    for (int i = 0; i < 4; ++i) {
        const int mbase = m0 + wr * 64 + i * 16 + (l4 << 2);
#pragma unroll
        for (int r = 0; r < 4; ++r) {
            const size_t rowoff = (size_t)(mbase + r) * HDIM + n0 + wn * 64 + l15;
#pragma unroll
            for (int j = 0; j < 4; ++j) {
                const float v = acc[i][j][r] + bvv[j];
                if (mode == 0)
                    ((u16*)outp)[rowoff + j * 16] = f2bf(silu_f(v));
                else
                    ((float*)outp)[rowoff + j * 16] = v;
            }
        }
    }
}

// ---------------------------------------------------------------------------
// Fused SiLU-attention + gating, 8-wave split + diagonal-branch (round-24),
// with the Wf2 transpose folded in: blocks [512,1536) each transpose one
// 64x64 tile of Wf2 into WTf (using the dynamic LDS buffer, 512 threads) —
// they run in the shadow of attention's causal tail imbalance.
__global__ __launch_bounds__(512) void attn_fused(
    const u16* __restrict__ Qb, const u16* __restrict__ Kb,
    const u16* __restrict__ VTg, const u16* __restrict__ Ub,
    const float* __restrict__ rel, u16* __restrict__ G,
    const float* __restrict__ Wf2, u16* __restrict__ WTf)
{
    extern __shared__ u16 alds[];

    if (blockIdx.x >= 512) {
        // ---- Wf2 transpose tile (512-thread variant, dynamic LDS) ----
        u16* T = alds;                         // [64][76]
        const int tid = blockIdx.x - 512;      // 0..1023
        const int r0 = (tid >> 5) * 64;        // k
        const int c0 = (tid & 31) * 64;        // n
        const int t = threadIdx.x;
#pragma unroll
        for (int c = t; c < 1024; c += 512) {
            const int r = c >> 4, cc = (c & 15) << 2;
            f32x4 v = *(const f32x4*)&Wf2[(size_t)(r0 + r) * HDIM + c0 + cc];
            u16x4 o;
#pragma unroll
            for (int j = 0; j < 4; ++j) o[j] = f2bf(v[j]);
            *(u16x4*)&T[r * 76 + cc] = o;
        }
        __syncthreads();
        {
            const int c = t & 511;             // 0..511, all used
            const int n = c >> 3, kc = (c & 7) << 3;
            u16x8 v;
#pragma unroll
            for (int j = 0; j < 8; ++j) v[j] = T[(kc + j) * 76 + n];
            *(u16x8*)&WTf[(size_t)(c0 + n) * HDIM + r0 + kc] = v;
        }
        return;
    }

    u16* Ps = alds + 24576;
    float* relh = (float*)(alds + 33792);

    const int idx = blockIdx.x;
    const int bh8 = idx & 7;
    const int j = (idx >> 3) & 7;
    const int bhhi = idx >> 6;            // 0..7
    const int bh = bhhi * 8 + bh8;
    const int b = bh >> 4, h = bh & 15;
    const int qS0 = j * 64;               // short subtile
    const int qL0 = (15 - j) * 64;        // long subtile
    const int nkt = 16 - j;
    const int t = threadIdx.x, lane = t & 63, w = t >> 6;    // 8 waves
    const int wq = w & 3;
    const bool isL = (w < 4);
    const int l15 = lane & 15, l4 = lane >> 4, l3 = lane >> 3;
    const size_t rowbase = (size_t)b * SEQLEN;
    const int col0 = h * HEADD;
    const float scale = 0.088388347648318447f;   // 1/sqrt(128)

    for (int i = t; i < 1024; i += 512) relh[i] = rel[(size_t)(1023 + i) * NHEADS + h];

    const u16* gK0 = Kb + (rowbase + w * 8 + l4) * HDIM + col0 + ((lane & 15) ^ l4) * 8;
    const u16* gK1 = Kb + (rowbase + w * 8 + 4 + l4) * HDIM + col0 + ((lane & 15) ^ (l4 + 4)) * 8;
    const u16* gV0 = VTg + ((size_t)bh * HEADD + w * 16 + l3) * SEQLEN + ((lane & 7) ^ l3) * 8;
    const u16* gV1 = VTg + ((size_t)bh * HEADD + w * 16 + 8 + l3) * SEQLEN + ((lane & 7) ^ l3) * 8;

    const int q0 = (isL ? qL0 : qS0) + wq * 16;
    bf16x8 aq[4];
#pragma unroll
    for (int dc = 0; dc < 4; ++dc)
        aq[dc] = *(const bf16x8*)&Qb[(rowbase + q0 + l15) * HDIM + col0 + dc * 32 + (l4 << 3)];

    f32x4 oacc[8] = {};
    const int prB = (isL ? 0 : 64) + wq * 16;     // Ps row base for this wave

#define STAGE_K(kt) do {                                                        \
    const size_t ko_ = (size_t)(kt) * 64 * HDIM;                                \
    glds16(gK0 + ko_, alds + w * 1024);                                         \
    glds16(gK1 + ko_, alds + w * 1024 + 512);                                   \
} while (0)
#define STAGE_V(kt, bsel) do {                                                  \
    u16* vb_ = alds + 8192 + ((bsel) ? 8192 : 0);                               \
    const size_t ko_ = (size_t)(kt) * 64;                                       \
    glds16(gV0 + ko_, vb_ + w * 1024);                                          \
    glds16(gV1 + ko_, vb_ + w * 1024 + 512);                                    \
} while (0)

    STAGE_K(0); STAGE_V(0, 0);
    asm volatile("s_waitcnt vmcnt(0)" ::: "memory");
    __builtin_amdgcn_s_barrier();

    int cur = 0;
#pragma unroll 1
    for (int kt = 0; kt < nkt; ++kt) {
        const int k0 = kt * 64;
        const bool act = isL || (kt <= j);        // wave-uniform
        const bool diag = isL ? (kt == nkt - 1) : (kt == j);
        if (kt + 1 < nkt) STAGE_V(kt + 1, cur ^ 1);
        const u16* kb = alds;
        const u16* vb = alds + 8192 + (cur ? 8192 : 0);

        // QK^T + rel (+ mask only on diag tile) + silu -> Ps
        if (act) {
#pragma unroll
            for (int kf = 0; kf < 4; ++kf) {
                const int krow = kf * 16 + l15;
                f32x4 s = {};
                __builtin_amdgcn_s_setprio(1);
#pragma unroll
                for (int dc = 0; dc < 4; ++dc) {
                    bf16x8 bk = *(const bf16x8*)&kb[krow * 128 + (((dc * 4 + l4) ^ (krow & 7)) << 3)];
                    s = __builtin_amdgcn_mfma_f32_16x16x32_bf16(aq[dc], bk, s, 0, 0, 0);
                }
                __builtin_amdgcn_s_setprio(0);
                const int kabs = k0 + krow;
                const int pr = prB + (l4 << 2);
                if (diag) {
#pragma unroll
                    for (int r = 0; r < 4; ++r) {
                        const int qabs = q0 + (l4 << 2) + r;
                        float v = 0.f;
                        if (kabs <= qabs) v = silu_f(fmaf(s[r], scale, relh[qabs - kabs]));
                        Ps[(pr + r) * 72 + kf * 16 + l15] = f2bf_t(v);
                    }
                } else {
#pragma unroll
                    for (int r = 0; r < 4; ++r) {
                        const int qabs = q0 + (l4 << 2) + r;
                        const float v = silu_f(fmaf(s[r], scale, relh[qabs - kabs]));
                        Ps[(pr + r) * 72 + kf * 16 + l15] = f2bf_t(v);
                    }
                }
            }
        }
        __builtin_amdgcn_s_barrier();                 // Kbuf free (QK^T reads done)
        if (kt + 1 < nkt) STAGE_K(kt + 1);

        // PV (active waves only)
        if (act) {
            bf16x8 ap[2];
#pragma unroll
            for (int kc = 0; kc < 2; ++kc)
                ap[kc] = *(const bf16x8*)&Ps[(prB + l15) * 72 + kc * 32 + (l4 << 3)];
            __builtin_amdgcn_s_setprio(1);
#pragma unroll
            for (int df = 0; df < 8; ++df) {
                const int vrow = df * 16 + l15;
#pragma unroll
                for (int kc = 0; kc < 2; ++kc) {
                    bf16x8 bv = *(const bf16x8*)&vb[vrow * 64 + (((kc * 4 + l4) ^ (vrow & 7)) << 3)];
                    oacc[df] = __builtin_amdgcn_mfma_f32_16x16x32_bf16(ap[kc], bv, oacc[df], 0, 0, 0);
                }
            }
            __builtin_amdgcn_s_setprio(0);
        }
        asm volatile("s_waitcnt vmcnt(0)" ::: "memory");  // next K,V landed
        __builtin_amdgcn_s_barrier();
        cur ^= 1;
    }
#undef STAGE_K
#undef STAGE_V

    // G = O * U (each wave its own 16 rows), row-sweep for coalescing
#pragma unroll
    for (int r = 0; r < 4; ++r) {
        const int qr = q0 + (l4 << 2) + r;
        const size_t row = (rowbase + qr) * HDIM + col0 + l15;
#pragma unroll
        for (int df = 0; df < 8; ++df)
            G[row + df * 16] = f2bf(oacc[df][r] * bf2f(Ub[row + df * 16]));
    }
}

// ---------------------------------------------------------------------------
extern "C" void kernel_launch(void* const* d_in, const int* in_sizes, int n_in,
                              void* d_out, int out_size, void* d_ws, size_t ws_size,
                              hipStream_t stream) {
    const float* query = (const float*)d_in[0];
    const float* key_  = (const float*)d_in[1];
    const float* value = (const float*)d_in[2];
    // d_in[3] attn_mask: causal by construction, handled analytically.
    const float* Wq  = (const float*)d_in[4];  const float* bq  = (const float*)d_in[5];
    const float* Wk  = (const float*)d_in[6];  const float* bk  = (const float*)d_in[7];
    const float* Wv  = (const float*)d_in[8];  const float* bv  = (const float*)d_in[9];
    const float* Wu  = (const float*)d_in[10]; const float* bu  = (const float*)d_in[11];
    const float* Wf2 = (const float*)d_in[12]; const float* bf2 = (const float*)d_in[13];
    const float* rel = (const float*)d_in[14];

    // Workspace (88 MiB): WTa 8 | Xbf 16 | Q(=G) 16 | K 16 | VTg 16 | U 16.
    // d_out (32 MiB, fully rewritten by the final GEMM) used as scratch for
    // key_bf (16 MiB) + Wv^T (8 MiB).
    char* ws = (char*)d_ws;
    const size_t WBYTES = (size_t)HDIM * HDIM * 2;   // 8 MiB
    const size_t ABYTES = (size_t)4096 * HDIM * 2;   // 16 MiB
    u16* WTa  = (u16*)ws;
    u16* Xbf  = (u16*)(ws + WBYTES);
    u16* Qbuf = (u16*)(ws + WBYTES + 1 * ABYTES);
    u16* Kbuf = (u16*)(ws + WBYTES + 2 * ABYTES);
    u16* VTg  = (u16*)(ws + WBYTES + 3 * ABYTES);    // V written transposed here
    u16* Ubuf = (u16*)(ws + WBYTES + 4 * ABYTES);
    u16* WTb  = VTg;           // borrowed for Wu^T: freed before V GEMM writes VTg
    u16* Gbuf = Qbuf;          // attn reads its own Q rows, then writes them as G
    u16* KXbf = (u16*)d_out;                 // scratch in d_out
    u16* WTv  = (u16*)((char*)d_out + ABYTES);

    dim3 tpb(256);
    const size_t GLDS  = 65536;  // 64 KiB for gemm128
    const size_t G8LDS = 131072; // 128 KiB for gemm256_8p
    const size_t ALDS  = 71680;  // 70 KiB for attn_fused

    aux_qu<<<6144, tpb, 0, stream>>>(query, Xbf, Wq, WTa, Wu, WTb);
    gemm256_8p<<<256, 512, G8LDS, stream>>>(Xbf, WTa, WTb, bq, bu, Qbuf, Ubuf);
    aux_kv<<<10240, tpb, 0, stream>>>(key_, KXbf, value, Xbf, Wk, WTa, Wv, WTv);
    gemm128<<<512, tpb, GLDS, stream>>>(KXbf, WTa, bk, Kbuf, 0);
    gemm128<<<512, tpb, GLDS, stream>>>(Xbf, WTv, bv, VTg, 2);
    // attn + folded Wf2 transpose (WTa is dead after the K GEMM)
    attn_fused<<<1536, 512, ALDS, stream>>>(Qbuf, Kbuf, VTg, Ubuf, rel, Gbuf,
                                            Wf2, WTa);
    gemm128<<<512, tpb, GLDS, stream>>>(Gbuf, WTa, bf2, d_out, 1);
}